// Round 16
// baseline (119.378 us; speedup 1.0000x reference)
//
#include <hip/hip_runtime.h>

#define DEV static __device__ __forceinline__

typedef __bf16 bf16x8 __attribute__((ext_vector_type(8)));
typedef __bf16 bf16x4 __attribute__((ext_vector_type(4)));
typedef float f32x4 __attribute__((ext_vector_type(4)));
typedef float f32x16 __attribute__((ext_vector_type(16)));
typedef unsigned int uint4v __attribute__((ext_vector_type(4)));
typedef unsigned short ushort4v __attribute__((ext_vector_type(4)));
using u16 = unsigned short;

#define NN 2048
#define DIMD 1024

DEV u16 f2bf(float f) {  // RNE via hardware cvt
    __bf16 b = (__bf16)f;
    return __builtin_bit_cast(u16, b);
}
DEV float bf2f(u16 s) {
    unsigned u = ((unsigned)s) << 16;
    return __builtin_bit_cast(float, u);
}
DEV bf16x8 load16(const u16* p) { return __builtin_bit_cast(bf16x8, *(const uint4v*)p); }
DEV f32x4 mfma16(bf16x8 a, bf16x8 b, f32x4 c) {
    return __builtin_amdgcn_mfma_f32_16x16x32_bf16(a, b, c, 0, 0, 0);
}
DEV f32x16 mfma32(bf16x8 a, bf16x8 b, f32x16 c) {
    return __builtin_amdgcn_mfma_f32_32x32x16_bf16(a, b, c, 0, 0, 0);
}
// async global->LDS, 16B per lane; lds base must be wave-uniform
DEV void gl_lds16(const u16* g, u16* l) {
    __builtin_amdgcn_global_load_lds((const __attribute__((address_space(1))) void*)g,
                                     (__attribute__((address_space(3))) void*)l, 16, 0, 0);
}

// ---------------- prep: W transposes (z<4) + x bf16 pack (z==4) ----------------

__global__ __launch_bounds__(256) void k_prep(const float* __restrict__ x,
                                              const float* __restrict__ s0,
                                              const float* __restrict__ s1,
                                              const float* __restrict__ s2,
                                              const float* __restrict__ s3,
                                              u16* __restrict__ xb,
                                              u16* __restrict__ wqkv_t,
                                              u16* __restrict__ wo_t) {
    __shared__ float tile[32][33];
    const int z = blockIdx.z;
    if (z < 4) {
        const float* src = (z == 0) ? s0 : (z == 1) ? s1 : (z == 2) ? s2 : s3;
        u16* dst = (z < 3) ? (wqkv_t + (size_t)z * 1024 * 1024) : wo_t;
        int tx = threadIdx.x & 31, ty = threadIdx.x >> 5;  // ty 0..7
        int kb = blockIdx.y * 32, nb = blockIdx.x * 32;
#pragma unroll
        for (int j = 0; j < 4; ++j)
            tile[ty + 8 * j][tx] = src[(size_t)(kb + ty + 8 * j) * 1024 + nb + tx];
        __syncthreads();
#pragma unroll
        for (int j = 0; j < 4; ++j)
            dst[(size_t)(nb + ty + 8 * j) * 1024 + kb + tx] = f2bf(tile[tx][ty + 8 * j]);
    } else {
        // pack x: 1,048,576 float4 -> bf16x4; 1024 blocks x 256 thr x 4 each
        const int bidx = blockIdx.y * 32 + blockIdx.x;
#pragma unroll
        for (int q = 0; q < 4; ++q) {
            int i = bidx * 1024 + q * 256 + threadIdx.x;
            float4 v = ((const float4*)x)[i];
            ushort4v o;
            o[0] = f2bf(v.x); o[1] = f2bf(v.y); o[2] = f2bf(v.z); o[3] = f2bf(v.w);
            *(ushort4v*)(xb + (size_t)i * 4) = o;
        }
    }
}

// ---------------- QKV GEMM v3: 256x256 tile, deep pipeline, counted vmcnt ----------------
// 512 thr (8 waves 2x4), BK=64, 2-tile LDS dbuf (128KB, 1 block/CU).
// Per tile t: {ds_read B + A-half0, lgkm, 32 MFMA} x2 halves -> barrier ->
// STAGE(t+2) -> vmcnt(8) [counted: waits only tile t+1's 8 older loads] ->
// barrier. Loads stay 2 tiles (~1200cyc) in flight; no drain-to-0 in loop.
// Swizzle: round-9 verified (pre-swizzled source col, swizzled ds_read chunk).
__global__ __launch_bounds__(512, 2) void k_gemm_qkv(const u16* __restrict__ A,
                                                     const u16* __restrict__ Bt,
                                                     const float* __restrict__ bq,
                                                     const float* __restrict__ bk,
                                                     const float* __restrict__ bv,
                                                     const float* __restrict__ qs,
                                                     const float* __restrict__ qb,
                                                     const float* __restrict__ ks,
                                                     const float* __restrict__ kb_,
                                                     u16* __restrict__ Qf,
                                                     u16* __restrict__ Kf,
                                                     u16* __restrict__ Vf) {
    __shared__ u16 As[2][256 * 64];  // 64KB
    __shared__ u16 Bs[2][256 * 64];  // 64KB
    const int K = 1024;
    const int m0 = blockIdx.x * 256, n0 = blockIdx.y * 256;
    const int tid = threadIdx.x;
    const int lane = tid & 63, w = tid >> 6;  // 8 waves
    const int wm = w >> 2, wn = w & 3;        // 2 x 4
    const int li = lane & 15, g = lane >> 4;
    const int l7 = li & 7;

    f32x4 acc[8][4] = {};

    // staging: wave w covers rows [w*32, w*32+32), 4 instrs x 8 rows (A and B)
    const int lr = lane >> 3;
    const int lc = (lane & 7) ^ lr;  // pre-swizzled source chunk
    const u16* gA = A + (size_t)(m0 + w * 32 + lr) * K + lc * 8;
    const u16* gB = Bt + (size_t)(n0 + w * 32 + lr) * K + lc * 8;

    auto STAGE = [&](int buf, int k0) {
        u16* lA = &As[buf][w * 2048];
        u16* lB = &Bs[buf][w * 2048];
#pragma unroll
        for (int i = 0; i < 4; ++i) {
            gl_lds16(gA + (size_t)(i * 8) * K + k0, lA + i * 512);
            gl_lds16(gB + (size_t)(i * 8) * K + k0, lB + i * 512);
        }
    };

    STAGE(0, 0);
    STAGE(1, 64);
    asm volatile("s_waitcnt vmcnt(8)" ::: "memory");  // tile 0 landed
    __syncthreads();

    for (int t = 0; t < 16; ++t) {
        const int cur = t & 1;
        const u16* as = As[cur];
        const u16* bs = Bs[cur];
        bf16x8 bfv[4][2], af[4][2];
#pragma unroll
        for (int ni = 0; ni < 4; ++ni) {
            const int row = wn * 64 + ni * 16 + li;
#pragma unroll
            for (int s = 0; s < 2; ++s)
                bfv[ni][s] = load16(&bs[row * 64 + (((s * 4 + g) ^ l7) * 8)]);
        }
#pragma unroll
        for (int mi = 0; mi < 4; ++mi) {
            const int row = wm * 128 + mi * 16 + li;
#pragma unroll
            for (int s = 0; s < 2; ++s)
                af[mi][s] = load16(&as[row * 64 + (((s * 4 + g) ^ l7) * 8)]);
        }
        asm volatile("s_waitcnt lgkmcnt(0)" ::: "memory");
        __builtin_amdgcn_sched_barrier(0);
        __builtin_amdgcn_s_setprio(1);
#pragma unroll
        for (int mi = 0; mi < 4; ++mi)
#pragma unroll
            for (int ni = 0; ni < 4; ++ni) {
                acc[mi][ni] = mfma16(af[mi][0], bfv[ni][0], acc[mi][ni]);
                acc[mi][ni] = mfma16(af[mi][1], bfv[ni][1], acc[mi][ni]);
            }
        __builtin_amdgcn_s_setprio(0);
        // second half: A m-tiles 4..7
#pragma unroll
        for (int mi = 0; mi < 4; ++mi) {
            const int row = wm * 128 + 64 + mi * 16 + li;
#pragma unroll
            for (int s = 0; s < 2; ++s)
                af[mi][s] = load16(&as[row * 64 + (((s * 4 + g) ^ l7) * 8)]);
        }
        asm volatile("s_waitcnt lgkmcnt(0)" ::: "memory");
        __builtin_amdgcn_sched_barrier(0);
        __builtin_amdgcn_s_setprio(1);
#pragma unroll
        for (int mi = 0; mi < 4; ++mi)
#pragma unroll
            for (int ni = 0; ni < 4; ++ni) {
                acc[mi + 4][ni] = mfma16(af[mi][0], bfv[ni][0], acc[mi + 4][ni]);
                acc[mi + 4][ni] = mfma16(af[mi][1], bfv[ni][1], acc[mi + 4][ni]);
            }
        __builtin_amdgcn_s_setprio(0);
        __syncthreads();                       // all reads of tile t complete
        if (t < 14) STAGE(cur, (t + 2) * 64);  // overwrite buf cur (safe post-barrier)
        if (t < 15) {
            if (t < 14)
                asm volatile("s_waitcnt vmcnt(8)" ::: "memory");  // t+1's loads done
            else
                asm volatile("s_waitcnt vmcnt(0)" ::: "memory");  // tail
            __syncthreads();                   // t+1 visible to ALL waves
        }
    }

    // ---- fused epilogue (per-wave 128x64 tile: mi 0..7) ----
    const int col0 = n0 + wn * 64;        // 64-aligned head segment base
    const int seg = col0 >> 10;           // 0=q, 1=k, 2=v
    const int hcol = col0 & 1023;
    const int h = hcol >> 6;

    if (seg < 2) {
        const float* S = (seg == 0) ? qs : ks;
        const float* Bb = (seg == 0) ? qb : kb_;
        const float* bias = (seg == 0) ? bq : bk;
        u16* dst = (seg == 0) ? Qf : Kf;
        const float sc = (seg == 0) ? -1.44269504f : 1.0f;  // fold -log2e into Q
        float lnS[4], lnB[4], bv4[4];
#pragma unroll
        for (int ni = 0; ni < 4; ++ni) {
            int d = ni * 16 + li;
            lnS[ni] = S[d] * sc; lnB[ni] = Bb[d] * sc; bv4[ni] = bias[hcol + d];
        }
#pragma unroll
        for (int mi = 0; mi < 8; ++mi) {
#pragma unroll
            for (int r = 0; r < 4; ++r) {
                float v0 = acc[mi][0][r] + bv4[0];
                float v1 = acc[mi][1][r] + bv4[1];
                float v2 = acc[mi][2][r] + bv4[2];
                float v3 = acc[mi][3][r] + bv4[3];
                float s1 = v0 + v1 + v2 + v3;
                float s2 = v0 * v0 + v1 * v1 + v2 * v2 + v3 * v3;
#pragma unroll
                for (int o = 1; o < 16; o <<= 1) {
                    s1 += __shfl_xor(s1, o);
                    s2 += __shfl_xor(s2, o);
                }
                float mu = s1 * (1.0f / 64.0f);
                float var = s2 * (1.0f / 64.0f) - mu * mu;
                float rsv = rsqrtf(var + 1e-6f);
                int row = m0 + wm * 128 + mi * 16 + 4 * g + r;
                int bseq = row >> 11, n = row & 2047;
                size_t base = ((size_t)(bseq * 16 + h)) * 131072 +
                              ((size_t)(n >> 5) * 4) * 512 + (size_t)(n & 31) * 8 +
                              (li >> 3) * 256 + (li & 7);
                dst[base + 0 * 512] = f2bf((v0 - mu) * rsv * lnS[0] + lnB[0]);
                dst[base + 1 * 512] = f2bf((v1 - mu) * rsv * lnS[1] + lnB[1]);
                dst[base + 2 * 512] = f2bf((v2 - mu) * rsv * lnS[2] + lnB[2]);
                dst[base + 3 * 512] = f2bf((v3 - mu) * rsv * lnS[3] + lnB[3]);
            }
        }
    } else {
        float bv4[4];
#pragma unroll
        for (int ni = 0; ni < 4; ++ni) bv4[ni] = bv[hcol + ni * 16 + li];
#pragma unroll
        for (int mi = 0; mi < 8; ++mi) {
#pragma unroll
            for (int r = 0; r < 4; ++r) {
                int row = m0 + wm * 128 + mi * 16 + 4 * g + r;
                int bseq = row >> 11, j = row & 2047;
                size_t vb_ = ((size_t)(bseq * 16 + h)) * 131072 +
                             ((size_t)((j >> 5) * 4 + ((j >> 4) & 1))) * 512 +
                             (size_t)(((j >> 3) & 1) * 32) * 8 + (j & 7);
#pragma unroll
                for (int ni = 0; ni < 4; ++ni)
                    Vf[vb_ + (ni >> 1) * 1024 + ((ni & 1) * 16 + li) * 8] =
                        f2bf(acc[mi][ni][r] + bv4[ni]);
            }
        }
    }
}

// ---------------- output GEMM (round-15 barrier-free per-wave form) ----------------
__global__ __launch_bounds__(256) void k_gemm_out(const u16* __restrict__ A,
                                                  const u16* __restrict__ Bt,
                                                  const float* __restrict__ bias,
                                                  const float* __restrict__ gamma,
                                                  float* __restrict__ out) {
    __shared__ u16 lds[4][2][64 * 32 * 2];  // 64KB
    const int K = 1024, ldc = 1024;
    const int m0 = blockIdx.x * 128, n0 = blockIdx.y * 128;
    const int tid = threadIdx.x;
    const int lane = tid & 63, w = tid >> 6;
    const int wr = w >> 1, wc = w & 1;
    const int li = lane & 15, g = lane >> 4;
    const int l7 = li & 7;

    f32x4 acc[4][4] = {};

    u16* lA = &lds[w][0][0];
    u16* lB = &lds[w][1][0];
    const int lr = lane >> 3;
    const int lc = (lane & 7) ^ lr;
    const u16* gA = A + (size_t)(m0 + wr * 64 + lr) * K + lc * 8;
    const u16* gB = Bt + (size_t)(n0 + wc * 64 + lr) * K + lc * 8;

    auto STAGE = [&](int k0) {
#pragma unroll
        for (int i = 0; i < 8; ++i) {
            gl_lds16(gA + (size_t)(i * 8) * K + k0, lA + i * 512);
            gl_lds16(gB + (size_t)(i * 8) * K + k0, lB + i * 512);
        }
    };

    STAGE(0);
    asm volatile("s_waitcnt vmcnt(0)" ::: "memory");

    for (int t = 0; t < 16; ++t) {
        bf16x8 af[4][2], bfv[4][2];
#pragma unroll
        for (int mi = 0; mi < 4; ++mi) {
            const int row = mi * 16 + li;
#pragma unroll
            for (int s = 0; s < 2; ++s)
                af[mi][s] = load16(&lA[row * 64 + (((s * 4 + g) ^ l7) * 8)]);
        }
#pragma unroll
        for (int ni = 0; ni < 4; ++ni) {
            const int row = ni * 16 + li;
#pragma unroll
            for (int s = 0; s < 2; ++s)
                bfv[ni][s] = load16(&lB[row * 64 + (((s * 4 + g) ^ l7) * 8)]);
        }
        asm volatile("s_waitcnt lgkmcnt(0)" ::: "memory");
        __builtin_amdgcn_sched_barrier(0);
        if (t < 15) STAGE((t + 1) * 64);
#pragma unroll
        for (int mi = 0; mi < 4; ++mi)
#pragma unroll
            for (int ni = 0; ni < 4; ++ni) {
                acc[mi][ni] = mfma16(af[mi][0], bfv[ni][0], acc[mi][ni]);
                acc[mi][ni] = mfma16(af[mi][1], bfv[ni][1], acc[mi][ni]);
            }
        asm volatile("s_waitcnt vmcnt(0)" ::: "memory");
    }

#pragma unroll
    for (int mi = 0; mi < 4; ++mi) {
        int row = m0 + wr * 64 + mi * 16 + 4 * g;
#pragma unroll
        for (int ni = 0; ni < 4; ++ni) {
            int col = n0 + wc * 64 + ni * 16 + li;
            float bv_ = bias[col], gv = gamma[col];
            f32x4 v = acc[mi][ni];
#pragma unroll
            for (int r = 0; r < 4; ++r)
                out[(size_t)(row + r) * ldc + col] = (v[r] + bv_) * gv;
        }
    }
}

// ---------------- fused sigmoid attention v11 (unchanged) ----------------
__global__ __launch_bounds__(256, 2) void k_attn(const u16* __restrict__ Qf,
                                                 const u16* __restrict__ Kf,
                                                 const u16* __restrict__ Vf,
                                                 const float* __restrict__ ib,
                                                 u16* __restrict__ attn_out) {
    __shared__ float red[2][64][65];
    const int bid = blockIdx.x;
    const int xcd = bid & 7, idx = bid >> 3;  // 1024 blocks: 128 per XCD
    const int bh = xcd * 4 + (idx >> 5);      // 4 bh per XCD -> K/V L2-resident
    const int iblk = idx & 31;
    const int b = bh >> 4, h = bh & 15;
    const int tid = threadIdx.x;
    const int jq = tid >> 6, lane = tid & 63;
    const int l32 = lane & 31, hi = lane >> 5;
    const float c0 = -ib[0] * 1.44269504f;  // acc init; Q pre-scaled by -log2e
    const u16* Qb = Qf + (size_t)bh * 131072;
    const u16* Kb = Kf + (size_t)bh * 131072;
    const u16* Vb = Vf + (size_t)bh * 131072;
    const int it0 = iblk * 2;

    bf16x8 qf[2][4];
#pragma unroll
    for (int t = 0; t < 2; ++t)
#pragma unroll
        for (int s = 0; s < 4; ++s)
            qf[t][s] = load16(Qb + ((size_t)((it0 + t) * 4 + s)) * 512 + lane * 8);

    f32x16 accO[2][2] = {};
    const u16* kb0 = Kb + (size_t)(jq * 16) * 2048;
    const u16* vb0 = Vb + (size_t)(jq * 16) * 2048;

    f32x16 cinit;
#pragma unroll
    for (int r = 0; r < 16; ++r) cinit[r] = c0;

    // prologue: K tiles 0,1; V tile 0; QK[t0][0]
    bf16x8 kf[2][4], vf[2][2][2];
#pragma unroll
    for (int s = 0; s < 4; ++s) kf[0][s] = load16(kb0 + s * 512 + lane * 8);
#pragma unroll
    for (int s = 0; s < 4; ++s) kf[1][s] = load16(kb0 + 2048 + s * 512 + lane * 8);
#pragma unroll
    for (int db = 0; db < 2; ++db)
#pragma unroll
        for (int js = 0; js < 2; ++js)
            vf[0][db][js] = load16(vb0 + (db * 2 + js) * 512 + lane * 8);
    f32x16 sa0 = cinit, sa1;
#pragma unroll
    for (int s = 0; s < 4; ++s) sa0 = mfma32(kf[0][s], qf[0][s], sa0);

#pragma unroll 2
    for (int jt = 0; jt < 16; ++jt) {
        const int cur = jt & 1, nxt = cur ^ 1;
        // prefetch V tile jt+1
        if (jt < 15) {
            const u16* vbn = vb0 + (size_t)(jt + 1) * 2048;
#pragma unroll
            for (int db = 0; db < 2; ++db)
#pragma unroll
                for (int js = 0; js < 2; ++js)
                    vf[nxt][db][js] = load16(vbn + (db * 2 + js) * 512 + lane * 8);
        }
        // QK[t1][jt]
        __builtin_amdgcn_s_setprio(1);
        sa1 = cinit;
#pragma unroll
        for (int s = 0; s < 4; ++s) sa1 = mfma32(kf[cur][s], qf[1][s], sa1);
        __builtin_amdgcn_s_setprio(0);
        // prefetch K tile jt+2
        if (jt < 14) {
            const u16* kbn = kb0 + (size_t)(jt + 2) * 2048;
#pragma unroll
            for (int s = 0; s < 4; ++s) kf[cur][s] = load16(kbn + s * 512 + lane * 8);
        }
        // sigmoid + pack t0 (sa0 from last iter)
        bf16x8 p00, p01;
        {
            float p[16];
#pragma unroll
            for (int r = 0; r < 16; ++r) {
                float e = __builtin_amdgcn_exp2f(sa0[r]);
                p[r] = __builtin_amdgcn_rcpf(1.0f + e);
            }
            unsigned wd[8];
#pragma unroll
            for (int u2 = 0; u2 < 8; ++u2) {
                unsigned r_;
                asm("v_cvt_pk_bf16_f32 %0, %1, %2"
                    : "=v"(r_) : "v"(p[2 * u2]), "v"(p[2 * u2 + 1]));
                wd[u2] = r_;
            }
            asm("v_permlane32_swap_b32 %0, %1" : "+v"(wd[0]), "+v"(wd[2]));
            asm("v_permlane32_swap_b32 %0, %1" : "+v"(wd[1]), "+v"(wd[3]));
            asm("v_permlane32_swap_b32 %0, %1" : "+v"(wd[4]), "+v"(wd[6]));
            asm("v_permlane32_swap_b32 %0, %1" : "+v"(wd[5]), "+v"(wd[7]));
            uint4v u0 = {wd[0], wd[1], wd[2], wd[3]};
            uint4v u1 = {wd[4], wd[5], wd[6], wd[7]};
            p00 = __builtin_bit_cast(bf16x8, u0);
            p01 = __builtin_bit_cast(bf16x8, u1);
        }
        // PV[t0][jt] + QK[t0][jt+1]
        __builtin_amdgcn_s_setprio(1);
        accO[0][0] = mfma32(vf[cur][0][0], p00, accO[0][0]);
        accO[0][0] = mfma32(vf[cur][0][1], p01, accO[0][0]);
        accO[0][1] = mfma32(vf[cur][1][0], p00, accO[0][1]);
        accO[0][1] = mfma32(vf[cur][1][1], p01, accO[0][1]);
        if (jt < 15) {
            sa0 = cinit;
#pragma unroll
            for (int s = 0; s < 4; ++s) sa0 = mfma32(kf[nxt][s], qf[0][s], sa0);
        }
        __builtin_amdgcn_s_setprio(0);
        // sigmoid + pack t1
        bf16x8 p10, p11;
        {
            float p[16];
#pragma unroll
            for (int r = 0; r < 16; ++r) {
                float e = __builtin_amdgcn_exp2f(sa1[r]);
                p[r] = __builtin_amdgcn_rcpf(1.0f + e);
            }
            unsigned wd[8];
#pragma unroll
            for (int u2 = 0; u2 < 8; ++u2) {
                unsigned r_;
                asm("v_cvt_pk_bf16_f32 %0, %1, %2"
                    : "=v"(r_) : "v"(p[2 * u2]), "v"(p[2 * u2 + 1]));
                wd[u2] = r_;
            }
            asm("v_permlane32_swap_b32 %0, %1" : "+v"(wd[0]), "+v"(wd[2]));
            asm("v_permlane32_swap_b32 %0, %1" : "+v"(wd[1]), "+v"(wd[3]));
            asm("v_permlane32_swap_b32 %0, %1" : "+v"(wd[4]), "+v"(wd[6]));
            asm("v_permlane32_swap_b32 %0, %1" : "+v"(wd[5]), "+v"(wd[7]));
            uint4v u0 = {wd[0], wd[1], wd[2], wd[3]};
            uint4v u1 = {wd[4], wd[5], wd[6], wd[7]};
            p10 = __builtin_bit_cast(bf16x8, u0);
            p11 = __builtin_bit_cast(bf16x8, u1);
        }
        // PV[t1][jt]
        __builtin_amdgcn_s_setprio(1);
        accO[1][0] = mfma32(vf[cur][0][0], p10, accO[1][0]);
        accO[1][0] = mfma32(vf[cur][0][1], p11, accO[1][0]);
        accO[1][1] = mfma32(vf[cur][1][0], p10, accO[1][1]);
        accO[1][1] = mfma32(vf[cur][1][1], p11, accO[1][1]);
        __builtin_amdgcn_s_setprio(0);
    }

    // cross-wave combine (d = db*32 + (r&3)+8(r>>2)+4hi)
    if (jq & 1) {
#pragma unroll
        for (int t = 0; t < 2; ++t)
#pragma unroll
            for (int db = 0; db < 2; ++db)
#pragma unroll
                for (int r = 0; r < 16; ++r)
                    red[jq >> 1][t * 32 + l32][db * 32 + (r & 3) + 8 * (r >> 2) + 4 * hi] =
                        accO[t][db][r];
    }
    __syncthreads();
    if (!(jq & 1)) {
#pragma unroll
        for (int t = 0; t < 2; ++t)
#pragma unroll
            for (int db = 0; db < 2; ++db)
#pragma unroll
                for (int r = 0; r < 16; ++r)
                    accO[t][db][r] +=
                        red[jq >> 1][t * 32 + l32][db * 32 + (r & 3) + 8 * (r >> 2) + 4 * hi];
    }
    __syncthreads();
    if (jq == 2) {
#pragma unroll
        for (int t = 0; t < 2; ++t)
#pragma unroll
            for (int db = 0; db < 2; ++db)
#pragma unroll
                for (int r = 0; r < 16; ++r)
                    red[0][t * 32 + l32][db * 32 + (r & 3) + 8 * (r >> 2) + 4 * hi] =
                        accO[t][db][r];
    }
    __syncthreads();
    if (jq == 0) {
#pragma unroll
        for (int t = 0; t < 2; ++t)
#pragma unroll
            for (int db = 0; db < 2; ++db)
#pragma unroll
                for (int r = 0; r < 16; ++r)
                    accO[t][db][r] +=
                        red[0][t * 32 + l32][db * 32 + (r & 3) + 8 * (r >> 2) + 4 * hi];
#pragma unroll
        for (int t = 0; t < 2; ++t) {
            const int i = it0 * 32 + t * 32 + l32;
#pragma unroll
            for (int db = 0; db < 2; ++db)
#pragma unroll
                for (int q = 0; q < 4; ++q) {
                    int d = db * 32 + 8 * q + 4 * hi;
                    bf16x4 o4;
#pragma unroll
                    for (int r = 0; r < 4; ++r) o4[r] = (__bf16)accO[t][db][4 * q + r];
                    *(bf16x4*)&attn_out[(size_t)(b * NN + i) * 1024 + h * 64 + d] = o4;
                }
        }
    }
}

// ---------------- launch ----------------

extern "C" void kernel_launch(void* const* d_in, const int* in_sizes, int n_in,
                              void* d_out, int out_size, void* d_ws, size_t ws_size,
                              hipStream_t stream) {
    (void)in_sizes; (void)n_in; (void)out_size; (void)ws_size;
    const float* x     = (const float*)d_in[0];
    const float* Wq    = (const float*)d_in[1];
    const float* bq    = (const float*)d_in[2];
    const float* Wk    = (const float*)d_in[3];
    const float* bk    = (const float*)d_in[4];
    const float* Wv    = (const float*)d_in[5];
    const float* bv    = (const float*)d_in[6];
    const float* qn_s  = (const float*)d_in[7];
    const float* qn_b  = (const float*)d_in[8];
    const float* kn_s  = (const float*)d_in[9];
    const float* kn_b  = (const float*)d_in[10];
    const float* ib    = (const float*)d_in[11];
    const float* Wo    = (const float*)d_in[12];
    const float* bo    = (const float*)d_in[13];
    const float* gamma = (const float*)d_in[14];
    float* out = (float*)d_out;

    char* ws = (char*)d_ws;
    size_t off = 0;
    auto alloc = [&](size_t bytes) -> void* {
        void* p = ws + off;
        off += (bytes + 255) & ~(size_t)255;
        return p;
    };
    u16* xb       = (u16*)alloc((size_t)4096 * 1024 * 2);   // x bf16
    u16* wqkv_t   = (u16*)alloc((size_t)3072 * 1024 * 2);   // [n][k]
    u16* wo_t     = (u16*)alloc((size_t)1024 * 1024 * 2);
    u16* Qf       = (u16*)alloc((size_t)32 * 131072 * 2);   // fragment-linear
    u16* Kf       = (u16*)alloc((size_t)32 * 131072 * 2);
    u16* Vf       = (u16*)alloc((size_t)32 * 131072 * 2);
    u16* attn_out = (u16*)alloc((size_t)4096 * 1024 * 2);

    k_prep<<<dim3(32, 32, 5), 256, 0, stream>>>(x, Wq, Wk, Wv, Wo, xb, wqkv_t, wo_t);
    k_gemm_qkv<<<dim3(16, 12), 512, 0, stream>>>(xb, wqkv_t, bq, bk, bv,
                                                 qn_s, qn_b, kn_s, kn_b, Qf, Kf, Vf);
    k_attn<<<1024, 256, 0, stream>>>(Qf, Kf, Vf, ib, attn_out);
    k_gemm_out<<<dim3(32, 8), 256, 0, stream>>>(attn_out, wo_t, bo, gamma, out);
}

// Round 17
// 106.509 us; speedup vs baseline: 1.1208x; 1.1208x over previous
//
#include <hip/hip_runtime.h>

#define DEV static __device__ __forceinline__

typedef __bf16 bf16x8 __attribute__((ext_vector_type(8)));
typedef __bf16 bf16x4 __attribute__((ext_vector_type(4)));
typedef float f32x4 __attribute__((ext_vector_type(4)));
typedef float f32x16 __attribute__((ext_vector_type(16)));
typedef unsigned int uint4v __attribute__((ext_vector_type(4)));
typedef unsigned short ushort4v __attribute__((ext_vector_type(4)));
using u16 = unsigned short;

#define NN 2048
#define DIMD 1024

DEV u16 f2bf(float f) {  // RNE via hardware cvt
    __bf16 b = (__bf16)f;
    return __builtin_bit_cast(u16, b);
}
DEV float bf2f(u16 s) {
    unsigned u = ((unsigned)s) << 16;
    return __builtin_bit_cast(float, u);
}
DEV bf16x8 load16(const u16* p) { return __builtin_bit_cast(bf16x8, *(const uint4v*)p); }
DEV f32x4 mfma16(bf16x8 a, bf16x8 b, f32x4 c) {
    return __builtin_amdgcn_mfma_f32_16x16x32_bf16(a, b, c, 0, 0, 0);
}
DEV f32x16 mfma32(bf16x8 a, bf16x8 b, f32x16 c) {
    return __builtin_amdgcn_mfma_f32_32x32x16_bf16(a, b, c, 0, 0, 0);
}
// async global->LDS, 16B per lane; lds base must be wave-uniform
DEV void gl_lds16(const u16* g, u16* l) {
    __builtin_amdgcn_global_load_lds((const __attribute__((address_space(1))) void*)g,
                                     (__attribute__((address_space(3))) void*)l, 16, 0, 0);
}

// ---------------- prep: W transposes (z<4) + x bf16 pack (z==4) ----------------

__global__ __launch_bounds__(256) void k_prep(const float* __restrict__ x,
                                              const float* __restrict__ s0,
                                              const float* __restrict__ s1,
                                              const float* __restrict__ s2,
                                              const float* __restrict__ s3,
                                              u16* __restrict__ xb,
                                              u16* __restrict__ wqkv_t,
                                              u16* __restrict__ wo_t) {
    __shared__ float tile[32][33];
    const int z = blockIdx.z;
    if (z < 4) {
        const float* src = (z == 0) ? s0 : (z == 1) ? s1 : (z == 2) ? s2 : s3;
        u16* dst = (z < 3) ? (wqkv_t + (size_t)z * 1024 * 1024) : wo_t;
        int tx = threadIdx.x & 31, ty = threadIdx.x >> 5;  // ty 0..7
        int kb = blockIdx.y * 32, nb = blockIdx.x * 32;
#pragma unroll
        for (int j = 0; j < 4; ++j)
            tile[ty + 8 * j][tx] = src[(size_t)(kb + ty + 8 * j) * 1024 + nb + tx];
        __syncthreads();
#pragma unroll
        for (int j = 0; j < 4; ++j)
            dst[(size_t)(nb + ty + 8 * j) * 1024 + kb + tx] = f2bf(tile[tx][ty + 8 * j]);
    } else {
        // pack x: 1,048,576 float4 -> bf16x4; 1024 blocks x 256 thr x 4 each
        const int bidx = blockIdx.y * 32 + blockIdx.x;
#pragma unroll
        for (int q = 0; q < 4; ++q) {
            int i = bidx * 1024 + q * 256 + threadIdx.x;
            float4 v = ((const float4*)x)[i];
            ushort4v o;
            o[0] = f2bf(v.x); o[1] = f2bf(v.y); o[2] = f2bf(v.z); o[3] = f2bf(v.w);
            *(ushort4v*)(xb + (size_t)i * 4) = o;
        }
    }
}

// ---------------- QKV GEMM v4: 128x64 tile (small-tile / high blocks-per-CU) ----------------
// grid 32x48 = 1536 blocks (~6/CU, LDS 24KB): independent barrier groups overlap
// each other's vmcnt drains (the mechanism behind k_gemm_out's ~850 TF).
// Wave w owns rows [w*32,+32) x all 64 cols (full head segment -> fused LN ok).
// BK=64, single-buffer, round-9 verified XOR swizzle.
__global__ __launch_bounds__(256) void k_gemm_qkv(const u16* __restrict__ A,
                                                  const u16* __restrict__ Bt,
                                                  const float* __restrict__ bq,
                                                  const float* __restrict__ bk,
                                                  const float* __restrict__ bv,
                                                  const float* __restrict__ qs,
                                                  const float* __restrict__ qb,
                                                  const float* __restrict__ ks,
                                                  const float* __restrict__ kb_,
                                                  u16* __restrict__ Qf,
                                                  u16* __restrict__ Kf,
                                                  u16* __restrict__ Vf) {
    __shared__ u16 As[128 * 64];  // 16KB
    __shared__ u16 Bs[64 * 64];   // 8KB
    const int K = 1024;
    const int m0 = blockIdx.x * 128, n0 = blockIdx.y * 64;
    const int tid = threadIdx.x;
    const int lane = tid & 63, w = tid >> 6;
    const int li = lane & 15, g = lane >> 4;
    const int l7 = li & 7;

    f32x4 acc[2][4] = {};

    const int lr = lane >> 3;
    const int lc = (lane & 7) ^ lr;  // pre-swizzled source chunk
    const u16* gA = A + (size_t)(m0 + w * 8 + lr) * K + lc * 8;
    const u16* gB = Bt + (size_t)(n0 + w * 8 + lr) * K + lc * 8;
    u16* lA = &As[w * 512];
    u16* lB = &Bs[w * 512];

    for (int k0 = 0; k0 < K; k0 += 64) {
        __syncthreads();
#pragma unroll
        for (int i = 0; i < 4; ++i)
            gl_lds16(gA + (size_t)(i * 32) * K + k0, lA + i * 2048);
#pragma unroll
        for (int i = 0; i < 2; ++i)
            gl_lds16(gB + (size_t)(i * 32) * K + k0, lB + i * 2048);
        asm volatile("s_waitcnt vmcnt(0)" ::: "memory");
        __syncthreads();
        bf16x8 af[2][2], bfv[4][2];
#pragma unroll
        for (int mi = 0; mi < 2; ++mi) {
            const int row = w * 32 + mi * 16 + li;
#pragma unroll
            for (int s = 0; s < 2; ++s)
                af[mi][s] = load16(&As[row * 64 + (((s * 4 + g) ^ l7) * 8)]);
        }
#pragma unroll
        for (int ni = 0; ni < 4; ++ni) {
            const int row = ni * 16 + li;
#pragma unroll
            for (int s = 0; s < 2; ++s)
                bfv[ni][s] = load16(&Bs[row * 64 + (((s * 4 + g) ^ l7) * 8)]);
        }
#pragma unroll
        for (int mi = 0; mi < 2; ++mi)
#pragma unroll
            for (int ni = 0; ni < 4; ++ni) {
                acc[mi][ni] = mfma16(af[mi][0], bfv[ni][0], acc[mi][ni]);
                acc[mi][ni] = mfma16(af[mi][1], bfv[ni][1], acc[mi][ni]);
            }
    }

    // ---- fused epilogue (wave owns full 64-col head segment) ----
    const int seg = n0 >> 10;           // 0=q, 1=k, 2=v
    const int hcol = n0 & 1023;
    const int h = hcol >> 6;

    if (seg < 2) {
        const float* S = (seg == 0) ? qs : ks;
        const float* Bb = (seg == 0) ? qb : kb_;
        const float* bias = (seg == 0) ? bq : bk;
        u16* dst = (seg == 0) ? Qf : Kf;
        const float sc = (seg == 0) ? -1.44269504f : 1.0f;  // fold -log2e into Q
        float lnS[4], lnB[4], bv4[4];
#pragma unroll
        for (int ni = 0; ni < 4; ++ni) {
            int d = ni * 16 + li;
            lnS[ni] = S[d] * sc; lnB[ni] = Bb[d] * sc; bv4[ni] = bias[hcol + d];
        }
#pragma unroll
        for (int mi = 0; mi < 2; ++mi) {
#pragma unroll
            for (int r = 0; r < 4; ++r) {
                float v0 = acc[mi][0][r] + bv4[0];
                float v1 = acc[mi][1][r] + bv4[1];
                float v2 = acc[mi][2][r] + bv4[2];
                float v3 = acc[mi][3][r] + bv4[3];
                float s1 = v0 + v1 + v2 + v3;
                float s2 = v0 * v0 + v1 * v1 + v2 * v2 + v3 * v3;
#pragma unroll
                for (int o = 1; o < 16; o <<= 1) {
                    s1 += __shfl_xor(s1, o);
                    s2 += __shfl_xor(s2, o);
                }
                float mu = s1 * (1.0f / 64.0f);
                float var = s2 * (1.0f / 64.0f) - mu * mu;
                float rsv = rsqrtf(var + 1e-6f);
                int row = m0 + w * 32 + mi * 16 + 4 * g + r;
                int bseq = row >> 11, n = row & 2047;
                size_t base = ((size_t)(bseq * 16 + h)) * 131072 +
                              ((size_t)(n >> 5) * 4) * 512 + (size_t)(n & 31) * 8 +
                              (li >> 3) * 256 + (li & 7);
                dst[base + 0 * 512] = f2bf((v0 - mu) * rsv * lnS[0] + lnB[0]);
                dst[base + 1 * 512] = f2bf((v1 - mu) * rsv * lnS[1] + lnB[1]);
                dst[base + 2 * 512] = f2bf((v2 - mu) * rsv * lnS[2] + lnB[2]);
                dst[base + 3 * 512] = f2bf((v3 - mu) * rsv * lnS[3] + lnB[3]);
            }
        }
    } else {
        float bv4[4];
#pragma unroll
        for (int ni = 0; ni < 4; ++ni) bv4[ni] = bv[hcol + ni * 16 + li];
#pragma unroll
        for (int mi = 0; mi < 2; ++mi) {
#pragma unroll
            for (int r = 0; r < 4; ++r) {
                int row = m0 + w * 32 + mi * 16 + 4 * g + r;
                int bseq = row >> 11, j = row & 2047;
                size_t vb_ = ((size_t)(bseq * 16 + h)) * 131072 +
                             ((size_t)((j >> 5) * 4 + ((j >> 4) & 1))) * 512 +
                             (size_t)(((j >> 3) & 1) * 32) * 8 + (j & 7);
#pragma unroll
                for (int ni = 0; ni < 4; ++ni)
                    Vf[vb_ + (ni >> 1) * 1024 + ((ni & 1) * 16 + li) * 8] =
                        f2bf(acc[mi][ni][r] + bv4[ni]);
            }
        }
    }
}

// ---------------- output GEMM: BK=64 + swizzle, 128x64 tile (round-9 form) ----------------
__global__ __launch_bounds__(256) void k_gemm_out(const u16* __restrict__ A,
                                                  const u16* __restrict__ Bt,
                                                  const float* __restrict__ bias,
                                                  const float* __restrict__ gamma,
                                                  float* __restrict__ out) {
    __shared__ u16 As[128 * 64];  // 16KB
    __shared__ u16 Bs[64 * 64];   // 8KB
    const int K = 1024, ldc = 1024;
    const int m0 = blockIdx.x * 128, n0 = blockIdx.y * 64;
    const int tid = threadIdx.x;
    const int lane = tid & 63, w = tid >> 6;
    const int wr = w >> 1, wc = w & 1;
    const int li = lane & 15, g = lane >> 4;
    const int l7 = li & 7;

    f32x4 acc[4][2] = {};

    const int lr = lane >> 3;
    const int lc = (lane & 7) ^ lr;
    const u16* gA = A + (size_t)(m0 + w * 8 + lr) * K + lc * 8;
    const u16* gB = Bt + (size_t)(n0 + w * 8 + lr) * K + lc * 8;
    u16* lA = &As[w * 512];
    u16* lB = &Bs[w * 512];

    for (int k0 = 0; k0 < K; k0 += 64) {
        __syncthreads();
#pragma unroll
        for (int i = 0; i < 4; ++i)
            gl_lds16(gA + (size_t)(i * 32) * K + k0, lA + i * 2048);
#pragma unroll
        for (int i = 0; i < 2; ++i)
            gl_lds16(gB + (size_t)(i * 32) * K + k0, lB + i * 2048);
        asm volatile("s_waitcnt vmcnt(0)" ::: "memory");
        __syncthreads();
        bf16x8 af[4][2], bfv[2][2];
#pragma unroll
        for (int mi = 0; mi < 4; ++mi) {
            const int row = wr * 64 + mi * 16 + li;
#pragma unroll
            for (int s = 0; s < 2; ++s)
                af[mi][s] = load16(&As[row * 64 + (((s * 4 + g) ^ l7) * 8)]);
        }
#pragma unroll
        for (int ni = 0; ni < 2; ++ni) {
            const int row = wc * 32 + ni * 16 + li;
#pragma unroll
            for (int s = 0; s < 2; ++s)
                bfv[ni][s] = load16(&Bs[row * 64 + (((s * 4 + g) ^ l7) * 8)]);
        }
#pragma unroll
        for (int mi = 0; mi < 4; ++mi)
#pragma unroll
            for (int ni = 0; ni < 2; ++ni) {
                acc[mi][ni] = mfma16(af[mi][0], bfv[ni][0], acc[mi][ni]);
                acc[mi][ni] = mfma16(af[mi][1], bfv[ni][1], acc[mi][ni]);
            }
    }

#pragma unroll
    for (int mi = 0; mi < 4; ++mi) {
        int row = m0 + wr * 64 + mi * 16 + 4 * g;
#pragma unroll
        for (int ni = 0; ni < 2; ++ni) {
            int col = n0 + wc * 32 + ni * 16 + li;
            float bv_ = bias[col], gv = gamma[col];
            f32x4 v = acc[mi][ni];
#pragma unroll
            for (int r = 0; r < 4; ++r)
                out[(size_t)(row + r) * ldc + col] = (v[r] + bv_) * gv;
        }
    }
}

// ---------------- fused sigmoid attention v11 (round-14 form, unchanged) ----------------
__global__ __launch_bounds__(256, 2) void k_attn(const u16* __restrict__ Qf,
                                                 const u16* __restrict__ Kf,
                                                 const u16* __restrict__ Vf,
                                                 const float* __restrict__ ib,
                                                 u16* __restrict__ attn_out) {
    __shared__ float red[2][64][65];
    const int bid = blockIdx.x;
    const int xcd = bid & 7, idx = bid >> 3;  // 1024 blocks: 128 per XCD
    const int bh = xcd * 4 + (idx >> 5);      // 4 bh per XCD -> K/V L2-resident
    const int iblk = idx & 31;
    const int b = bh >> 4, h = bh & 15;
    const int tid = threadIdx.x;
    const int jq = tid >> 6, lane = tid & 63;
    const int l32 = lane & 31, hi = lane >> 5;
    const float c0 = -ib[0] * 1.44269504f;  // acc init; Q pre-scaled by -log2e
    const u16* Qb = Qf + (size_t)bh * 131072;
    const u16* Kb = Kf + (size_t)bh * 131072;
    const u16* Vb = Vf + (size_t)bh * 131072;
    const int it0 = iblk * 2;

    bf16x8 qf[2][4];
#pragma unroll
    for (int t = 0; t < 2; ++t)
#pragma unroll
        for (int s = 0; s < 4; ++s)
            qf[t][s] = load16(Qb + ((size_t)((it0 + t) * 4 + s)) * 512 + lane * 8);

    f32x16 accO[2][2] = {};
    const u16* kb0 = Kb + (size_t)(jq * 16) * 2048;
    const u16* vb0 = Vb + (size_t)(jq * 16) * 2048;

    f32x16 cinit;
#pragma unroll
    for (int r = 0; r < 16; ++r) cinit[r] = c0;

    // prologue: K tiles 0,1; V tile 0; QK[t0][0]
    bf16x8 kf[2][4], vf[2][2][2];
#pragma unroll
    for (int s = 0; s < 4; ++s) kf[0][s] = load16(kb0 + s * 512 + lane * 8);
#pragma unroll
    for (int s = 0; s < 4; ++s) kf[1][s] = load16(kb0 + 2048 + s * 512 + lane * 8);
#pragma unroll
    for (int db = 0; db < 2; ++db)
#pragma unroll
        for (int js = 0; js < 2; ++js)
            vf[0][db][js] = load16(vb0 + (db * 2 + js) * 512 + lane * 8);
    f32x16 sa0 = cinit, sa1;
#pragma unroll
    for (int s = 0; s < 4; ++s) sa0 = mfma32(kf[0][s], qf[0][s], sa0);

#pragma unroll 2
    for (int jt = 0; jt < 16; ++jt) {
        const int cur = jt & 1, nxt = cur ^ 1;
        // prefetch V tile jt+1
        if (jt < 15) {
            const u16* vbn = vb0 + (size_t)(jt + 1) * 2048;
#pragma unroll
            for (int db = 0; db < 2; ++db)
#pragma unroll
                for (int js = 0; js < 2; ++js)
                    vf[nxt][db][js] = load16(vbn + (db * 2 + js) * 512 + lane * 8);
        }
        // QK[t1][jt]
        __builtin_amdgcn_s_setprio(1);
        sa1 = cinit;
#pragma unroll
        for (int s = 0; s < 4; ++s) sa1 = mfma32(kf[cur][s], qf[1][s], sa1);
        __builtin_amdgcn_s_setprio(0);
        // prefetch K tile jt+2
        if (jt < 14) {
            const u16* kbn = kb0 + (size_t)(jt + 2) * 2048;
#pragma unroll
            for (int s = 0; s < 4; ++s) kf[cur][s] = load16(kbn + s * 512 + lane * 8);
        }
        // sigmoid + pack t0 (sa0 from last iter)
        bf16x8 p00, p01;
        {
            float p[16];
#pragma unroll
            for (int r = 0; r < 16; ++r) {
                float e = __builtin_amdgcn_exp2f(sa0[r]);
                p[r] = __builtin_amdgcn_rcpf(1.0f + e);
            }
            unsigned wd[8];
#pragma unroll
            for (int u2 = 0; u2 < 8; ++u2) {
                unsigned r_;
                asm("v_cvt_pk_bf16_f32 %0, %1, %2"
                    : "=v"(r_) : "v"(p[2 * u2]), "v"(p[2 * u2 + 1]));
                wd[u2] = r_;
            }
            asm("v_permlane32_swap_b32 %0, %1" : "+v"(wd[0]), "+v"(wd[2]));
            asm("v_permlane32_swap_b32 %0, %1" : "+v"(wd[1]), "+v"(wd[3]));
            asm("v_permlane32_swap_b32 %0, %1" : "+v"(wd[4]), "+v"(wd[6]));
            asm("v_permlane32_swap_b32 %0, %1" : "+v"(wd[5]), "+v"(wd[7]));
            uint4v u0 = {wd[0], wd[1], wd[2], wd[3]};
            uint4v u1 = {wd[4], wd[5], wd[6], wd[7]};
            p00 = __builtin_bit_cast(bf16x8, u0);
            p01 = __builtin_bit_cast(bf16x8, u1);
        }
        // PV[t0][jt] + QK[t0][jt+1]
        __builtin_amdgcn_s_setprio(1);
        accO[0][0] = mfma32(vf[cur][0][0], p00, accO[0][0]);
        accO[0][0] = mfma32(vf[cur][0][1], p01, accO[0][0]);
        accO[0][1] = mfma32(vf[cur][1][0], p00, accO[0][1]);
        accO[0][1] = mfma32(vf[cur][1][1], p01, accO[0][1]);
        if (jt < 15) {
            sa0 = cinit;
#pragma unroll
            for (int s = 0; s < 4; ++s) sa0 = mfma32(kf[nxt][s], qf[0][s], sa0);
        }
        __builtin_amdgcn_s_setprio(0);
        // sigmoid + pack t1
        bf16x8 p10, p11;
        {
            float p[16];
#pragma unroll
            for (int r = 0; r < 16; ++r) {
                float e = __builtin_amdgcn_exp2f(sa1[r]);
                p[r] = __builtin_amdgcn_rcpf(1.0f + e);
            }
            unsigned wd[8];
#pragma unroll
            for (int u2 = 0; u2 < 8; ++u2) {
                unsigned r_;
                asm("v_cvt_pk_bf16_f32 %0, %1, %2"
                    : "=v"(r_) : "v"(p[2 * u2]), "v"(p[2 * u2 + 1]));
                wd[u2] = r_;
            }
            asm("v_permlane32_swap_b32 %0, %1" : "+v"(wd[0]), "+v"(wd[2]));
            asm("v_permlane32_swap_b32 %0, %1" : "+v"(wd[1]), "+v"(wd[3]));
            asm("v_permlane32_swap_b32 %0, %1" : "+v"(wd[4]), "+v"(wd[6]));
            asm("v_permlane32_swap_b32 %0, %1" : "+v"(wd[5]), "+v"(wd[7]));
            uint4v u0 = {wd[0], wd[1], wd[2], wd[3]};
            uint4v u1 = {wd[4], wd[5], wd[6], wd[7]};
            p10 = __builtin_bit_cast(bf16x8, u0);
            p11 = __builtin_bit_cast(bf16x8, u1);
        }
        // PV[t1][jt]
        __builtin_amdgcn_s_setprio(1);
        accO[1][0] = mfma32(vf[cur][0][0], p10, accO[1][0]);
        accO[1][0] = mfma32(vf[cur][0][1], p11, accO[1][0]);
        accO[1][1] = mfma32(vf[cur][1][0], p10, accO[1][1]);
        accO[1][1] = mfma32(vf[cur][1][1], p11, accO[1][1]);
        __builtin_amdgcn_s_setprio(0);
    }

    // cross-wave combine (d = db*32 + (r&3)+8(r>>2)+4hi)
    if (jq & 1) {
#pragma unroll
        for (int t = 0; t < 2; ++t)
#pragma unroll
            for (int db = 0; db < 2; ++db)
#pragma unroll
                for (int r = 0; r < 16; ++r)
                    red[jq >> 1][t * 32 + l32][db * 32 + (r & 3) + 8 * (r >> 2) + 4 * hi] =
                        accO[t][db][r];
    }
    __syncthreads();
    if (!(jq & 1)) {
#pragma unroll
        for (int t = 0; t < 2; ++t)
#pragma unroll
            for (int db = 0; db < 2; ++db)
#pragma unroll
                for (int r = 0; r < 16; ++r)
                    accO[t][db][r] +=
                        red[jq >> 1][t * 32 + l32][db * 32 + (r & 3) + 8 * (r >> 2) + 4 * hi];
    }
    __syncthreads();
    if (jq == 2) {
#pragma unroll
        for (int t = 0; t < 2; ++t)
#pragma unroll
            for (int db = 0; db < 2; ++db)
#pragma unroll
                for (int r = 0; r < 16; ++r)
                    red[0][t * 32 + l32][db * 32 + (r & 3) + 8 * (r >> 2) + 4 * hi] =
                        accO[t][db][r];
    }
    __syncthreads();
    if (jq == 0) {
#pragma unroll
        for (int t = 0; t < 2; ++t)
#pragma unroll
            for (int db = 0; db < 2; ++db)
#pragma unroll
                for (int r = 0; r < 16; ++r)
                    accO[t][db][r] +=
                        red[0][t * 32 + l32][db * 32 + (r & 3) + 8 * (r >> 2) + 4 * hi];
#pragma unroll
        for (int t = 0; t < 2; ++t) {
            const int i = it0 * 32 + t * 32 + l32;
#pragma unroll
            for (int db = 0; db < 2; ++db)
#pragma unroll
                for (int q = 0; q < 4; ++q) {
                    int d = db * 32 + 8 * q + 4 * hi;
                    bf16x4 o4;
#pragma unroll
                    for (int r = 0; r < 4; ++r) o4[r] = (__bf16)accO[t][db][4 * q + r];
                    *(bf16x4*)&attn_out[(size_t)(b * NN + i) * 1024 + h * 64 + d] = o4;
                }
        }
    }
}

// ---------------- launch ----------------

extern "C" void kernel_launch(void* const* d_in, const int* in_sizes, int n_in,
                              void* d_out, int out_size, void* d_ws, size_t ws_size,
                              hipStream_t stream) {
    (void)in_sizes; (void)n_in; (void)out_size; (void)ws_size;
    const float* x     = (const float*)d_in[0];
    const float* Wq    = (const float*)d_in[1];
    const float* bq    = (const float*)d_in[2];
    const float* Wk    = (const float*)d_in[3];
    const float* bk    = (const float*)d_in[4];
    const float* Wv    = (const float*)d_in[5];
    const float* bv    = (const float*)d_in[6];
    const float* qn_s  = (const float*)d_in[7];
    const float* qn_b  = (const float*)d_in[8];
    const float* kn_s  = (const float*)d_in[9];
    const float* kn_b  = (const float*)d_in[10];
    const float* ib    = (const float*)d_in[11];
    const float* Wo    = (const float*)d_in[12];
    const float* bo    = (const float*)d_in[13];
    const float* gamma = (const float*)d_in[14];
    float* out = (float*)d_out;

    char* ws = (char*)d_ws;
    size_t off = 0;
    auto alloc = [&](size_t bytes) -> void* {
        void* p = ws + off;
        off += (bytes + 255) & ~(size_t)255;
        return p;
    };
    u16* xb       = (u16*)alloc((size_t)4096 * 1024 * 2);   // x bf16
    u16* wqkv_t   = (u16*)alloc((size_t)3072 * 1024 * 2);   // [n][k]
    u16* wo_t     = (u16*)alloc((size_t)1024 * 1024 * 2);
    u16* Qf       = (u16*)alloc((size_t)32 * 131072 * 2);   // fragment-linear
    u16* Kf       = (u16*)alloc((size_t)32 * 131072 * 2);
    u16* Vf       = (u16*)alloc((size_t)32 * 131072 * 2);
    u16* attn_out = (u16*)alloc((size_t)4096 * 1024 * 2);

    k_prep<<<dim3(32, 32, 5), 256, 0, stream>>>(x, Wq, Wk, Wv, Wo, xb, wqkv_t, wo_t);
    k_gemm_qkv<<<dim3(32, 48), 256, 0, stream>>>(xb, wqkv_t, bq, bk, bv,
                                                 qn_s, qn_b, kn_s, kn_b, Qf, Kf, Vf);
    k_attn<<<1024, 256, 0, stream>>>(Qf, Kf, Vf, ib, attn_out);
    k_gemm_out<<<dim3(32, 16), 256, 0, stream>>>(attn_out, wo_t, bo, gamma, out);
}